// Round 8
// baseline (1084.335 us; speedup 1.0000x reference)
//
#include <hip/hip_runtime.h>

#define S_LEN 2048
#define DIN   50
#define H     64

// tanh(v) = 1 - 2/(exp(2v)+1); ~1e-6 rel err, exact at +/-inf
__device__ __forceinline__ float tanh_fast(float v) {
    float e = __builtin_amdgcn_exp2f(v * 2.885390082f);   // exp(2v)
    return 1.0f - 2.0f * __builtin_amdgcn_rcpf(e + 1.0f);
}

// Sum over the eight 8-lane groups: every lane ends with sum over kg of
// v[8*kg + (lane&7)].  Level-8 via DPP row_ror:8 (xor-8 pairing within each
// 16-lane row, full-rate VALU); levels 16/32 via permlane swaps (proven R3/R6).
__device__ __forceinline__ float red8(float v) {
#if __has_builtin(__builtin_amdgcn_update_dpp)
    float t = __uint_as_float((unsigned)__builtin_amdgcn_update_dpp(
        0, (int)__float_as_uint(v), 0x128 /*row_ror:8*/, 0xF, 0xF, true));
    v += t;
#else
    v += __shfl_xor(v, 8, 64);
#endif
#if __has_builtin(__builtin_amdgcn_permlane16_swap) && __has_builtin(__builtin_amdgcn_permlane32_swap)
    typedef unsigned u2 __attribute__((ext_vector_type(2)));
    u2 r = __builtin_amdgcn_permlane16_swap(__float_as_uint(v), __float_as_uint(v), false, false);
    float s = __uint_as_float(r[0]) + __uint_as_float(r[1]);
    u2 q = __builtin_amdgcn_permlane32_swap(__float_as_uint(s), __float_as_uint(s), false, false);
    return __uint_as_float(q[0]) + __uint_as_float(q[1]);
#else
    v += __shfl_xor(v, 16, 64);
    v += __shfl_xor(v, 32, 64);
    return v;
#endif
}

__global__ __launch_bounds__(512)
__attribute__((amdgpu_waves_per_eu(4, 4)))   // 4096 waves = exactly 4/EU; VGPR budget 128
void rnn_fused(const float* __restrict__ x,
               const float* __restrict__ W_ih0, const float* __restrict__ W_hh0,
               const float* __restrict__ b_ih0, const float* __restrict__ b_hh0,
               const float* __restrict__ W_ih1, const float* __restrict__ W_hh1,
               const float* __restrict__ b_ih1, const float* __restrict__ b_hh1,
               const float* __restrict__ W1, const float* __restrict__ b1,
               const float* __restrict__ W2, const float* __restrict__ b2,
               float* __restrict__ out)
{
    const int b    = blockIdx.x;
    const int tid  = threadIdx.x;
    const int lane = tid & 63;
    const int w    = tid >> 6;      // wave id: outputs [8w, 8w+8)
    const int j    = lane & 7;      // output within chunk
    const int kg   = lane >> 3;     // k-group (8-way k-split within wave)
    const int outj = 8 * w + j;     // this lane's output unit

    __shared__ __align__(16) float xs[2][8][8];   // x row: 7-wide chunks padded to 8
    __shared__ __align__(16) float h1s[H];
    __shared__ __align__(16) float h2s[H];

    // ---- per-lane weights, register-resident (31 floats) ----
    float wx[7];
    #pragma unroll
    for (int i = 0; i < 7; ++i) {
        int c = 7 * kg + i;
        wx[i] = (c < DIN) ? W_ih0[outj * DIN + c] : 0.0f;
    }
    float whh0_l[8], wih1_l[8], whh1_l[8];
    #pragma unroll
    for (int i = 0; i < 8; ++i) {
        whh0_l[i] = W_hh0[outj * H + 8 * kg + i];
        wih1_l[i] = W_ih1[outj * H + 8 * kg + i];
        whh1_l[i] = W_hh1[outj * H + 8 * kg + i];
    }
    const float bias0 = b_ih0[outj] + b_hh0[outj];
    const float bias1 = b_ih1[outj] + b_hh1[outj];

    const float* __restrict__ xrow = x + (size_t)b * (size_t)(S_LEN * DIN);

    // staging slots (wave 0): slot (sw, sj) <- x[s*DIN + 7*sw + sj]
    const int  sw   = lane >> 3, sj = lane & 7;
    const int  scol = 7 * sw + sj;
    const bool sval = (tid < 64) && (sj < 7) && (scol < DIN);

    if (tid < 64) xs[0][sw][sj] = sval ? xrow[scol] : 0.0f;
    float pfA = sval ? xrow[1 * DIN + scol] : 0.0f;
    float pfB = sval ? xrow[2 * DIN + scol] : 0.0f;
    const float* xpf = xrow + 3 * DIN + scol;

    float h1c[8], h2c[8];    // h-state chunk kg in registers
    #pragma unroll
    for (int i = 0; i < 8; ++i) { h1c[i] = 0.0f; h2c[i] = 0.0f; }

    __syncthreads();   // xs[0] visible

    // x-projection partial for s=0 (chunk kg: 7 values)
    float xacc;
    {
        float4 xv0 = *(const float4*)&xs[0][kg][0];
        float4 xv1 = *(const float4*)&xs[0][kg][4];
        float a0 = xv0.x * wx[0], a1 = xv0.y * wx[1];
        a0 = fmaf(xv0.z, wx[2], a0);  a1 = fmaf(xv0.w, wx[3], a1);
        a0 = fmaf(xv1.x, wx[4], a0);  a1 = fmaf(xv1.y, wx[5], a1);
        a0 = fmaf(xv1.z, wx[6], a0);
        xacc = a0 + a1;
    }

#define STEP_BODY(CUR, NXT, PFOK)                                              \
    {                                                                          \
        /* stage 1: xacc + whh0-chunk . h1c (old) — registers only */          \
        float a0 = xacc, a1 = 0.0f;                                            \
        _Pragma("unroll")                                                      \
        for (int q = 0; q < 4; ++q) {                                          \
            a0 = fmaf(h1c[2 * q + 0], whh0_l[2 * q + 0], a0);                  \
            a1 = fmaf(h1c[2 * q + 1], whh0_l[2 * q + 1], a1);                  \
        }                                                                      \
        float h1n = tanh_fast(red8(a0 + a1) + bias0);                          \
        /* fillers: stage next x row, rotate prefetch */                       \
        if (tid < 64) xs[NXT][sw][sj] = pfA;                                   \
        pfA = pfB;                                                             \
        pfB = (sval && (PFOK)) ? *xpf : 0.0f;                                  \
        xpf += DIN;                                                            \
        /* filler: stage-2 h2-part (h2c from prev B2) */                       \
        float c0 = 0.0f, c1 = 0.0f;                                            \
        _Pragma("unroll")                                                      \
        for (int q = 0; q < 4; ++q) {                                          \
            c0 = fmaf(h2c[2 * q + 0], whh1_l[2 * q + 0], c0);                  \
            c1 = fmaf(h2c[2 * q + 1], whh1_l[2 * q + 1], c1);                  \
        }                                                                      \
        if (kg == 0) h1s[8 * w + j] = h1n;                                     \
        __syncthreads();   /* B1: h1_new + staged x visible */                 \
        /* reload h1 chunk in place */                                         \
        *(float4*)&h1c[0] = *(const float4*)&h1s[8 * kg + 0];                  \
        *(float4*)&h1c[4] = *(const float4*)&h1s[8 * kg + 4];                  \
        /* x-projection partial for next step (fills ds_read bubble) */        \
        float4 xv0 = *(const float4*)&xs[NXT][kg][0];                          \
        float4 xv1 = *(const float4*)&xs[NXT][kg][4];                          \
        float xn0 = xv0.x * wx[0], xn1 = xv0.y * wx[1];                        \
        xn0 = fmaf(xv0.z, wx[2], xn0);  xn1 = fmaf(xv0.w, wx[3], xn1);         \
        xn0 = fmaf(xv1.x, wx[4], xn0);  xn1 = fmaf(xv1.y, wx[5], xn1);         \
        xn0 = fmaf(xv1.z, wx[6], xn0);                                         \
        /* stage 2: wih1-part on fresh h1c */                                  \
        float c2 = 0.0f, c3 = 0.0f;                                            \
        _Pragma("unroll")                                                      \
        for (int q = 0; q < 4; ++q) {                                          \
            c2 = fmaf(h1c[2 * q + 0], wih1_l[2 * q + 0], c2);                  \
            c3 = fmaf(h1c[2 * q + 1], wih1_l[2 * q + 1], c3);                  \
        }                                                                      \
        float h2n = tanh_fast(red8((c0 + c2) + (c1 + c3)) + bias1);            \
        if (kg == 0) h2s[8 * w + j] = h2n;                                     \
        __syncthreads();   /* B2: h2_new visible */                            \
        *(float4*)&h2c[0] = *(const float4*)&h2s[8 * kg + 0];                  \
        *(float4*)&h2c[4] = *(const float4*)&h2s[8 * kg + 4];                  \
        xacc = xn0 + xn1;                                                      \
    }

    for (int s = 0; s < S_LEN; s += 2) {
        STEP_BODY(0, 1, s + 3 < S_LEN)
        STEP_BODY(1, 0, s + 4 < S_LEN)
    }
#undef STEP_BODY

    // ---- head: relu(h2 @ W1^T + b1) -> sigmoid(. @ W2^T + b2) ----
    if (tid < 64) {
        float hv = 0.0f;
        if (lane < 32) {
            float acc = b1[lane];
            #pragma unroll
            for (int k = 0; k < H; ++k)
                acc = fmaf(h2s[k], W1[lane * H + k], acc);
            hv = fmaxf(acc, 0.0f) * W2[lane];
        }
        #pragma unroll
        for (int off = 32; off; off >>= 1)
            hv += __shfl_xor(hv, off, 64);
        if (lane == 0)
            out[b] = 1.0f / (1.0f + __expf(-(hv + b2[0])));
    }
}

extern "C" void kernel_launch(void* const* d_in, const int* in_sizes, int n_in,
                              void* d_out, int out_size, void* d_ws, size_t ws_size,
                              hipStream_t stream) {
    const float* x     = (const float*)d_in[0];
    const float* W_ih0 = (const float*)d_in[1];
    const float* W_hh0 = (const float*)d_in[2];
    const float* b_ih0 = (const float*)d_in[3];
    const float* b_hh0 = (const float*)d_in[4];
    const float* W_ih1 = (const float*)d_in[5];
    const float* W_hh1 = (const float*)d_in[6];
    const float* b_ih1 = (const float*)d_in[7];
    const float* b_hh1 = (const float*)d_in[8];
    const float* W1    = (const float*)d_in[9];
    const float* b1    = (const float*)d_in[10];
    const float* W2    = (const float*)d_in[11];
    const float* b2    = (const float*)d_in[12];
    float* out = (float*)d_out;

    rnn_fused<<<dim3(512), dim3(512), 0, stream>>>(
        x, W_ih0, W_hh0, b_ih0, b_hh0,
        W_ih1, W_hh1, b_ih1, b_hh1,
        W1, b1, W2, b2, out);
}